// Round 11
// baseline (334.415 us; speedup 1.0000x reference)
//
#include <hip/hip_runtime.h>
#include <cstddef>

#define T_STEPS 256
#define OBS     32
#define ACTD    8
#define NB      8       // real sequences per block (MFMA N-cols 8..15 are dead)
#define HPAD    80      // h row stride in f16 (160 B, stride 40 dwords -> 0 conflicts, R7-proven)
#define NSEQ    4096

typedef _Float16 f16x8 __attribute__((ext_vector_type(8)));
typedef _Float16 f16x2 __attribute__((ext_vector_type(2)));
typedef float    f32x4 __attribute__((ext_vector_type(4)));

union F8 { f16x8 v; _Float16 e[8]; f16x2 h2[4]; };

#define LOG2E 1.44269504088896f

__device__ __forceinline__ float fsig(float x) {
    return __builtin_amdgcn_rcpf(1.0f + __builtin_amdgcn_exp2f(x * -LOG2E));
}
__device__ __forceinline__ float ftanh(float x) {
    return 2.0f * __builtin_amdgcn_rcpf(1.0f + __builtin_amdgcn_exp2f(x * (-2.0f * LOG2E))) - 1.0f;
}
__device__ __forceinline__ f16x2 pkrtz(float a, float b) {
    return __builtin_bit_cast(f16x2, __builtin_amdgcn_cvt_pkrtz(a, b));
}

__global__ __launch_bounds__(256, 2)
void lstm_fused(const float* __restrict__ obss, const float* __restrict__ actions,
                const float* __restrict__ W, const float* __restrict__ b,
                const float* __restrict__ Wdec, const float* __restrict__ bdec_p,
                float* __restrict__ out)
{
    // Transposed GEMM: D[gate-col][seq] = W^T (A, static regs) x [h|x]^T (B).
    // h LDS: row = seq, col = phi(unit); phi(u)=(u&3)+4*((u>>4)&1)+8*((u>>2)&3)+32*(u>>5)
    // 16 rows allocated; rows 8..15 carry bounded fake state (zero x forever).
    __shared__ __align__(16) _Float16 Ahi[2][16 * HPAD];
    __shared__ __align__(16) _Float16 Alo[2][16 * HPAD];
    __shared__ float partb[2][16][20];    // [buf][seq][16 partials]

    const int tid  = threadIdx.x;
    const int w    = tid >> 6;            // wave 0..3
    const int lane = tid & 63;
    const int g    = lane >> 4;           // k-group / D-row-group
    const int m    = lane & 15;           // seq (B col / D col); A row = gate-col 64e+16w+m
    const int n0   = blockIdx.x * NB;
    const int u0   = 16 * w + 4 * g;      // first of 4 units this lane updates
    const int sigb = 32 * (w >> 1) + 8 * g + 4 * (w & 1);  // = phi(u0)

    // ---- one-time: W^T fragments as A operands (plain f16; h hi/lo is B-side) ----
    f16x8 Ahh[4][2], Axo[4], AxA[4];
    {
        const float* Wc = W + 16 * w + m;     // tile e -> gate-col 64e + 16w + m
#pragma unroll
        for (int e = 0; e < 4; e++) {
#pragma unroll
            for (int c = 0; c < 2; c++) {
                F8 hi;
#pragma unroll
                for (int i = 0; i < 8; i++) {
                    int k = 32 * c + 16 * (i >> 2) + 4 * g + (i & 3);  // h-k 0..63
                    hi.e[i] = (_Float16)Wc[(40 + k) * 256 + 64 * e];
                }
                Ahh[e][c] = hi.v;
            }
            F8 xo, xA;
#pragma unroll
            for (int i = 0; i < 8; i++) {
                int d = 16 * (i >> 2) + 4 * g + (i & 3);               // 0..31
                xo.e[i] = (_Float16)Wc[d * 256 + 64 * e];
                xA.e[i] = (d < ACTD) ? (_Float16)Wc[(OBS + d) * 256 + 64 * e]
                                     : (_Float16)0.0f;                 // act, zero-padded K32
            }
            Axo[e] = xo.v;
            AxA[e] = xA.v;
        }
    }
    // per-lane vector biases / decode weights for units u0..u0+3
    f32x4 bIv = *(const f32x4*)&b[u0];
    f32x4 bJv = *(const f32x4*)&b[64 + u0];
    f32x4 bFv = *(const f32x4*)&b[128 + u0];
    bFv[0] += 1.0f; bFv[1] += 1.0f; bFv[2] += 1.0f; bFv[3] += 1.0f;
    f32x4 bOv = *(const f32x4*)&b[192 + u0];
    f32x4 wdv = *(const f32x4*)&Wdec[u0];
    const float bd = bdec_p[0];

    for (int i = tid; i < 2 * 16 * HPAD; i += 256) {
        (&Ahi[0][0])[i] = (_Float16)0.0f;
        (&Alo[0][0])[i] = (_Float16)0.0f;
    }
    __syncthreads();

    // per-lane x prefetch: real seqs only (m < NB); running pointers
    const float* pO = obss    + ((size_t)(n0 + m) * T_STEPS) * OBS  + 4 * g;
    const float* pA = actions + ((size_t)(n0 + m) * T_STEPS) * ACTD + 4 * g;
    f32x4 xo0 = {0,0,0,0}, xo1 = {0,0,0,0}, xa = {0,0,0,0};
    auto loadx = [&]() {
        if (m < NB) {
            xo0 = *(const f32x4*)pO;
            xo1 = *(const f32x4*)(pO + 16);
            pO += OBS;
            if (g < 2) { xa = *(const f32x4*)pA; pA += ACTD; }
        }
    };
    loadx();
    f32x4 cr = {0.f, 0.f, 0.f, 0.f};      // c state: units u0..u0+3 of seq m
    float* pOut = out + n0 + tid;         // running output pointer (tid<NB lanes)

#pragma unroll 2
    for (int t = 0; t < T_STEPS; ++t) {
        const int cb  = t & 1;
        const int nb2 = cb ^ 1;
        // LDS-only barrier: x prefetch (vmcnt) may span it
        asm volatile("s_waitcnt lgkmcnt(0)\n\ts_barrier" ::: "memory");

        // B h-fragments: seq row m, phi-contiguous b128 slices (cols 0..63)
        const _Float16* bh = &Ahi[cb][m * HPAD];
        const _Float16* bl = &Alo[cb][m * HPAD];
        f16x8 bh0 = *(const f16x8*)(bh + 8 * g);          // k 0..31
        f16x8 bh1 = *(const f16x8*)(bh + 32 + 8 * g);     // k 32..63
        f16x8 bl0 = *(const f16x8*)(bl + 8 * g);
        f16x8 bl1 = *(const f16x8*)(bl + 32 + 8 * g);

        if (t > 0 && tid < NB) {
            float o = bd;
#pragma unroll
            for (int k2 = 0; k2 < 16; k2++) o += partb[nb2][tid][k2];
            *pOut = o;
            pOut += NSEQ;
        }

        // B x-fragments from prefetched regs (packed cvt; act zero-padded to K32)
        F8 uo;
        uo.h2[0] = pkrtz(xo0[0], xo0[1]);
        uo.h2[1] = pkrtz(xo0[2], xo0[3]);
        uo.h2[2] = pkrtz(xo1[0], xo1[1]);
        uo.h2[3] = pkrtz(xo1[2], xo1[3]);
        F8 uA;
        uA.h2[0] = pkrtz(xa[0], xa[1]);
        uA.h2[1] = pkrtz(xa[2], xa[3]);
        uA.h2[2] = pkrtz(0.0f, 0.0f);
        uA.h2[3] = pkrtz(0.0f, 0.0f);
        f16x8 bxo = uo.v;
        f16x8 bxA = uA.v;
        if (t + 1 < T_STEPS) loadx();

        // 4 independent tiles (gate e), single 6-deep K32 chain each
        f32x4 acc[4];
        __builtin_amdgcn_s_setprio(1);
#pragma unroll
        for (int e = 0; e < 4; e++) {
            f32x4 a = {0.f, 0.f, 0.f, 0.f};
            a = __builtin_amdgcn_mfma_f32_16x16x32_f16(Axo[e], bxo, a, 0, 0, 0);
            a = __builtin_amdgcn_mfma_f32_16x16x32_f16(AxA[e], bxA, a, 0, 0, 0);
            a = __builtin_amdgcn_mfma_f32_16x16x32_f16(Ahh[e][0], bh0, a, 0, 0, 0);
            a = __builtin_amdgcn_mfma_f32_16x16x32_f16(Ahh[e][1], bh1, a, 0, 0, 0);
            a = __builtin_amdgcn_mfma_f32_16x16x32_f16(Ahh[e][0], bl0, a, 0, 0, 0);
            a = __builtin_amdgcn_mfma_f32_16x16x32_f16(Ahh[e][1], bl1, a, 0, 0, 0);
            acc[e] = a;
        }
        __builtin_amdgcn_s_setprio(0);

        // cell update: 4 units (u0+r) of seq m; scalar h/lo writes (proven pattern)
        float p = 0.0f;
#pragma unroll
        for (int r = 0; r < 4; r++) {
            float gi = acc[0][r] + bIv[r];
            float gj = acc[1][r] + bJv[r];
            float gf = acc[2][r] + bFv[r];
            float go = acc[3][r] + bOv[r];
            float c  = cr[r] * fsig(gf) + fsig(gi) * ftanh(gj);
            cr[r] = c;
            float h = ftanh(c) * fsig(go);
            _Float16 hv = (_Float16)h;
            Ahi[nb2][m * HPAD + sigb + r] = hv;
            Alo[nb2][m * HPAD + sigb + r] = (_Float16)(h - (float)hv);
            p = fmaf(h, wdv[r], p);
        }
        partb[cb][m][4 * w + g] = p;
    }

    __syncthreads();
    if (tid < NB) {
        float o = bd;
#pragma unroll
        for (int k2 = 0; k2 < 16; k2++) o += partb[1][tid][k2];
        *pOut = o;
    }
}

extern "C" void kernel_launch(void* const* d_in, const int* in_sizes, int n_in,
                              void* d_out, int out_size, void* d_ws, size_t ws_size,
                              hipStream_t stream) {
    (void)in_sizes; (void)n_in; (void)d_ws; (void)ws_size; (void)out_size;
    const float* obss    = (const float*)d_in[0];
    const float* actions = (const float*)d_in[1];
    const float* W       = (const float*)d_in[2];
    const float* b       = (const float*)d_in[3];
    const float* Wdec    = (const float*)d_in[4];
    const float* bdec    = (const float*)d_in[5];
    float* out = (float*)d_out;
    lstm_fused<<<dim3(NSEQ / NB), dim3(256), 0, stream>>>(obss, actions, W, b, Wdec, bdec, out);
}

// Round 12
// 289.018 us; speedup vs baseline: 1.1571x; 1.1571x over previous
//
#include <hip/hip_runtime.h>
#include <cstddef>

#define T_STEPS 256
#define OBS     32
#define ACTD    8
#define NB      16      // sequences per block (full N-dim of transposed MFMA)
#define HPAD    80      // h row stride in f16 (160 B)
#define NSEQ    4096

typedef _Float16 f16x8 __attribute__((ext_vector_type(8)));
typedef _Float16 f16x4 __attribute__((ext_vector_type(4)));
typedef _Float16 f16x2 __attribute__((ext_vector_type(2)));
typedef float    f32x4 __attribute__((ext_vector_type(4)));

union F8 { f16x8 v; _Float16 e[8]; f16x2 h2[4]; };
union F4 { f16x4 v; _Float16 e[4]; f16x2 h2[2]; };

#define LOG2E 1.44269504088896f

__device__ __forceinline__ float fsig(float x) {
    return __builtin_amdgcn_rcpf(1.0f + __builtin_amdgcn_exp2f(x * -LOG2E));
}
__device__ __forceinline__ float ftanh(float x) {
    return 2.0f * __builtin_amdgcn_rcpf(1.0f + __builtin_amdgcn_exp2f(x * (-2.0f * LOG2E))) - 1.0f;
}
__device__ __forceinline__ f16x2 pkrtz(float a, float b) {
    return __builtin_bit_cast(f16x2, __builtin_amdgcn_cvt_pkrtz(a, b));
}

__global__ __launch_bounds__(256)
void lstm_fused(const float* __restrict__ obss, const float* __restrict__ actions,
                const float* __restrict__ W, const float* __restrict__ b,
                const float* __restrict__ Wdec, const float* __restrict__ bdec_p,
                float* __restrict__ out)
{
    // Transposed GEMM: D[gate-col][seq] = W^T (A, static regs) x [h|x]^T (B).
    // h LDS: row = seq, col = phi(unit); phi(u)=(u&3)+4*((u>>4)&1)+8*((u>>2)&3)+32*(u>>5)
    // Biases ride the MFMA through the act-tile's k=8 slot (B=1.0 there).
    __shared__ __align__(16) _Float16 Ahi[2][NB * HPAD];
    __shared__ __align__(16) _Float16 Alo[2][NB * HPAD];
    __shared__ __align__(16) float partb[2][16][4];   // [buf][seq][wave]

    const int tid  = threadIdx.x;
    const int w    = tid >> 6;            // wave 0..3
    const int lane = tid & 63;
    const int g    = lane >> 4;           // k-group / D-row-group
    const int m    = lane & 15;           // seq (B col / D col); A row = gate-col 64e+16w+m
    const int n0   = blockIdx.x * NB;
    const int u0   = 16 * w + 4 * g;      // first of 4 units this lane updates
    const int sigb = 32 * (w >> 1) + 8 * g + 4 * (w & 1);  // = phi(u0), 8B-aligned

    // ---- one-time: W^T fragments as A operands (plain f16; h hi/lo is B-side) ----
    f16x8 Ahh[4][2], Axo[4], AxA[4];
    {
        const float* Wc = W + 16 * w + m;     // tile e -> gate-col 64e + 16w + m
#pragma unroll
        for (int e = 0; e < 4; e++) {
#pragma unroll
            for (int c = 0; c < 2; c++) {
                F8 hi;
#pragma unroll
                for (int i = 0; i < 8; i++) {
                    int k = 32 * c + 16 * (i >> 2) + 4 * g + (i & 3);  // h-k 0..63
                    hi.e[i] = (_Float16)Wc[(40 + k) * 256 + 64 * e];
                }
                Ahh[e][c] = hi.v;
            }
            F8 xo, xA;
            // bias for this lane's A-row (gate-col 64e+16w+m); forget gate +1.0
            float bv = b[64 * e + 16 * w + m] + (e == 2 ? 1.0f : 0.0f);
#pragma unroll
            for (int i = 0; i < 8; i++) {
                int d = 16 * (i >> 2) + 4 * g + (i & 3);               // 0..31
                xo.e[i] = (_Float16)Wc[d * 256 + 64 * e];
                xA.e[i] = (d < ACTD) ? (_Float16)Wc[(OBS + d) * 256 + 64 * e]
                        : (d == 8)   ? (_Float16)bv
                                     : (_Float16)0.0f;                 // act tile, K32-padded
            }
            Axo[e] = xo.v;
            AxA[e] = xA.v;
        }
    }
    f32x4 wdv = *(const f32x4*)&Wdec[u0];
    const float bd = bdec_p[0];

    for (int i = tid; i < 2 * NB * HPAD; i += 256) {
        (&Ahi[0][0])[i] = (_Float16)0.0f;
        (&Alo[0][0])[i] = (_Float16)0.0f;
    }
    __syncthreads();

    // per-lane x prefetch: seq m, dim-slice by g; running pointers
    const float* pO = obss    + ((size_t)(n0 + m) * T_STEPS) * OBS  + 4 * g;
    const float* pA = actions + ((size_t)(n0 + m) * T_STEPS) * ACTD + 4 * g;
    f32x4 xo0 = {0,0,0,0}, xo1 = {0,0,0,0}, xa = {0,0,0,0};
    auto loadx = [&]() {
        xo0 = *(const f32x4*)pO;
        xo1 = *(const f32x4*)(pO + 16);
        pO += OBS;
        if (g < 2) { xa = *(const f32x4*)pA; pA += ACTD; }
    };
    loadx();
    f32x4 cr = {0.f, 0.f, 0.f, 0.f};      // c state: units u0..u0+3 of seq m

    // rotating output duty: wave w serves steps t with t&3 == w (row t-1)
    float* pOut = out + (size_t)((w + 3) & 3) * NSEQ + n0 + lane;

#pragma unroll 2
    for (int t = 0; t < T_STEPS; ++t) {
        const int cb  = t & 1;
        const int nb2 = cb ^ 1;
        // LDS-only barrier: x prefetch (vmcnt) may span it
        asm volatile("s_waitcnt lgkmcnt(0)\n\ts_barrier" ::: "memory");

        // B h-fragments: seq row m, phi-contiguous b128 slices (cols 0..63)
        const _Float16* bh = &Ahi[cb][m * HPAD];
        const _Float16* bl = &Alo[cb][m * HPAD];
        f16x8 bh0 = *(const f16x8*)(bh + 8 * g);          // k 0..31
        f16x8 bh1 = *(const f16x8*)(bh + 32 + 8 * g);     // k 32..63
        f16x8 bl0 = *(const f16x8*)(bl + 8 * g);
        f16x8 bl1 = *(const f16x8*)(bl + 32 + 8 * g);

        // output duty (rotates): one b128 read + 3 adds + store on one wave
        if (t > 0 && w == (t & 3) && lane < 16) {
            f32x4 pv = *(const f32x4*)&partb[nb2][lane][0];
            *pOut = pv[0] + pv[1] + pv[2] + pv[3] + bd;
            pOut += 4 * NSEQ;
        }

        // B x-fragments from prefetched regs (packed cvt; k=8 slot carries 1.0)
        F8 uo;
        uo.h2[0] = pkrtz(xo0[0], xo0[1]);
        uo.h2[1] = pkrtz(xo0[2], xo0[3]);
        uo.h2[2] = pkrtz(xo1[0], xo1[1]);
        uo.h2[3] = pkrtz(xo1[2], xo1[3]);
        F8 uA;
        uA.h2[0] = pkrtz(g == 2 ? 1.0f : xa[0], xa[1]);
        uA.h2[1] = pkrtz(xa[2], xa[3]);
        uA.h2[2] = pkrtz(0.0f, 0.0f);
        uA.h2[3] = pkrtz(0.0f, 0.0f);
        f16x8 bxo = uo.v;
        f16x8 bxA = uA.v;
        if (t + 1 < T_STEPS) loadx();

        // 4 independent tiles (gate e), single 6-deep K32 chain each
        f32x4 acc[4];
        __builtin_amdgcn_s_setprio(1);
#pragma unroll
        for (int e = 0; e < 4; e++) {
            f32x4 a = {0.f, 0.f, 0.f, 0.f};
            a = __builtin_amdgcn_mfma_f32_16x16x32_f16(Axo[e], bxo, a, 0, 0, 0);
            a = __builtin_amdgcn_mfma_f32_16x16x32_f16(AxA[e], bxA, a, 0, 0, 0);
            a = __builtin_amdgcn_mfma_f32_16x16x32_f16(Ahh[e][0], bh0, a, 0, 0, 0);
            a = __builtin_amdgcn_mfma_f32_16x16x32_f16(Ahh[e][1], bh1, a, 0, 0, 0);
            a = __builtin_amdgcn_mfma_f32_16x16x32_f16(Ahh[e][0], bl0, a, 0, 0, 0);
            a = __builtin_amdgcn_mfma_f32_16x16x32_f16(Ahh[e][1], bl1, a, 0, 0, 0);
            acc[e] = a;
        }
        __builtin_amdgcn_s_setprio(0);

        // cell update: 4 units (u0+r) of seq m; biases already in acc
        float h4[4];
#pragma unroll
        for (int r = 0; r < 4; r++) {
            float c = cr[r] * fsig(acc[2][r]) + fsig(acc[0][r]) * ftanh(acc[1][r]);
            cr[r] = c;
            h4[r] = ftanh(c) * fsig(acc[3][r]);
        }
        // pack hi/lo and write as two b64 (phi layout, 8B-aligned)
        F4 hi_;
        hi_.h2[0] = pkrtz(h4[0], h4[1]);
        hi_.h2[1] = pkrtz(h4[2], h4[3]);
        F4 lo_;
        lo_.h2[0] = pkrtz(h4[0] - (float)hi_.e[0], h4[1] - (float)hi_.e[1]);
        lo_.h2[1] = pkrtz(h4[2] - (float)hi_.e[2], h4[3] - (float)hi_.e[3]);
        *(f16x4*)(&Ahi[nb2][m * HPAD + sigb]) = hi_.v;
        *(f16x4*)(&Alo[nb2][m * HPAD + sigb]) = lo_.v;

        // decode partial: 4 in-lane FMAs, then g-reduce via shfl butterfly
        float p = h4[0] * wdv[0];
        p = fmaf(h4[1], wdv[1], p);
        p = fmaf(h4[2], wdv[2], p);
        p = fmaf(h4[3], wdv[3], p);
        p += __shfl_xor(p, 16);
        p += __shfl_xor(p, 32);
        if (lane < 16) partb[cb][lane][w] = p;   // lane==m here
    }

    // final row (t = T_STEPS-1 partials live in partb[1]); duty wave = 0
    __syncthreads();
    if (w == 0 && lane < 16) {
        f32x4 pv = *(const f32x4*)&partb[1][lane][0];
        *pOut = pv[0] + pv[1] + pv[2] + pv[3] + bd;
    }
}

extern "C" void kernel_launch(void* const* d_in, const int* in_sizes, int n_in,
                              void* d_out, int out_size, void* d_ws, size_t ws_size,
                              hipStream_t stream) {
    (void)in_sizes; (void)n_in; (void)d_ws; (void)ws_size; (void)out_size;
    const float* obss    = (const float*)d_in[0];
    const float* actions = (const float*)d_in[1];
    const float* W       = (const float*)d_in[2];
    const float* b       = (const float*)d_in[3];
    const float* Wdec    = (const float*)d_in[4];
    const float* bdec    = (const float*)d_in[5];
    float* out = (float*)d_out;
    lstm_fused<<<dim3(NSEQ / NB), dim3(256), 0, stream>>>(obss, actions, W, b, Wdec, bdec, out);
}

// Round 13
// 197.734 us; speedup vs baseline: 1.6912x; 1.4616x over previous
//
#include <hip/hip_runtime.h>
#include <cstddef>

#define T_STEPS 256
#define OBS     32
#define ACTD    8
#define NB      16      // sequences per block (full N-dim of transposed MFMA)
#define HPAD    88      // h row stride in f16 (176 B; 44 dw stride -> <=2-way banks)
#define NSEQ    4096

typedef _Float16 f16x8 __attribute__((ext_vector_type(8)));
typedef _Float16 f16x4 __attribute__((ext_vector_type(4)));
typedef _Float16 f16x2 __attribute__((ext_vector_type(2)));
typedef float    f32x4 __attribute__((ext_vector_type(4)));

union F8 { f16x8 v; _Float16 e[8]; f16x2 h2[4]; };
union F4 { f16x4 v; _Float16 e[4]; f16x2 h2[2]; };

#define LOG2E 1.44269504088896f

__device__ __forceinline__ float fsig(float x) {
    return __builtin_amdgcn_rcpf(1.0f + __builtin_amdgcn_exp2f(x * -LOG2E));
}
__device__ __forceinline__ float ftanh(float x) {
    return 2.0f * __builtin_amdgcn_rcpf(1.0f + __builtin_amdgcn_exp2f(x * (-2.0f * LOG2E))) - 1.0f;
}
__device__ __forceinline__ f16x2 pkrtz(float a, float b) {
    return __builtin_bit_cast(f16x2, __builtin_amdgcn_cvt_pkrtz(a, b));
}

__global__ __launch_bounds__(256)
void lstm_fused(const float* __restrict__ obss, const float* __restrict__ actions,
                const float* __restrict__ W, const float* __restrict__ b,
                const float* __restrict__ Wdec, const float* __restrict__ bdec_p,
                float* __restrict__ out)
{
    // Transposed GEMM: D[gate-col][seq] = W^T (A, static regs) x [h|x]^T (B).
    // h LDS: row = seq, col = phi(unit); phi(u)=(u&3)+4*((u>>4)&1)+8*((u>>2)&3)+32*(u>>5)
    // Biases ride the MFMA through the act-tile's k=8 slot (B=1.0 there).
    __shared__ __align__(16) _Float16 Ahi[2][NB * HPAD];
    __shared__ __align__(16) _Float16 Alo[2][NB * HPAD];
    __shared__ __align__(16) float partb[2][16][20];   // [buf][seq][16 partials (4w+g)]

    const int tid  = threadIdx.x;
    const int w    = tid >> 6;            // wave 0..3
    const int lane = tid & 63;
    const int g    = lane >> 4;           // k-group / D-row-group
    const int m    = lane & 15;           // seq (B col / D col); A row = gate-col 64e+16w+m
    const int n0   = blockIdx.x * NB;
    const int u0   = 16 * w + 4 * g;      // first of 4 units this lane updates
    const int sigb = 32 * (w >> 1) + 8 * g + 4 * (w & 1);  // = phi(u0), 8B-aligned

    // ---- one-time: W^T fragments as A operands (plain f16; h hi/lo is B-side) ----
    f16x8 Ahh[4][2], Axo[4], AxA[4];
    {
        const float* Wc = W + 16 * w + m;     // tile e -> gate-col 64e + 16w + m
#pragma unroll
        for (int e = 0; e < 4; e++) {
#pragma unroll
            for (int c = 0; c < 2; c++) {
                F8 hi;
#pragma unroll
                for (int i = 0; i < 8; i++) {
                    int k = 32 * c + 16 * (i >> 2) + 4 * g + (i & 3);  // h-k 0..63
                    hi.e[i] = (_Float16)Wc[(40 + k) * 256 + 64 * e];
                }
                Ahh[e][c] = hi.v;
            }
            F8 xo, xA;
            // bias for this lane's A-row (gate-col 64e+16w+m); forget gate +1.0
            float bv = b[64 * e + 16 * w + m] + (e == 2 ? 1.0f : 0.0f);
#pragma unroll
            for (int i = 0; i < 8; i++) {
                int d = 16 * (i >> 2) + 4 * g + (i & 3);               // 0..31
                xo.e[i] = (_Float16)Wc[d * 256 + 64 * e];
                xA.e[i] = (d < ACTD) ? (_Float16)Wc[(OBS + d) * 256 + 64 * e]
                        : (d == 8)   ? (_Float16)bv
                                     : (_Float16)0.0f;                 // act tile, K32-padded
            }
            Axo[e] = xo.v;
            AxA[e] = xA.v;
        }
    }
    f32x4 wdv = *(const f32x4*)&Wdec[u0];
    const float bd = bdec_p[0];

    for (int i = tid; i < 2 * NB * HPAD; i += 256) {
        (&Ahi[0][0])[i] = (_Float16)0.0f;
        (&Alo[0][0])[i] = (_Float16)0.0f;
    }
    __syncthreads();

    // per-lane x: seq m, dim-slice by g; running pointers. cvt runs at prev-step tail.
    const float* pO = obss    + ((size_t)(n0 + m) * T_STEPS) * OBS  + 4 * g;
    const float* pA = actions + ((size_t)(n0 + m) * T_STEPS) * ACTD + 4 * g;
    f32x4 xo0 = {0,0,0,0}, xo1 = {0,0,0,0}, xa = {0,0,0,0};
    auto loadx = [&]() {
        xo0 = *(const f32x4*)pO;
        xo1 = *(const f32x4*)(pO + 16);
        pO += OBS;
        if (g < 2) { xa = *(const f32x4*)pA; pA += ACTD; }
    };
    f16x8 bxo, bxA;                       // persistent B x-fragments (carry over barrier)
    auto cvtx = [&]() {
        F8 uo;
        uo.h2[0] = pkrtz(xo0[0], xo0[1]);
        uo.h2[1] = pkrtz(xo0[2], xo0[3]);
        uo.h2[2] = pkrtz(xo1[0], xo1[1]);
        uo.h2[3] = pkrtz(xo1[2], xo1[3]);
        F8 uA;
        uA.h2[0] = pkrtz(g == 2 ? 1.0f : xa[0], xa[1]);   // k=8 slot carries 1.0 (bias row)
        uA.h2[1] = pkrtz(xa[2], xa[3]);
        uA.h2[2] = pkrtz(0.0f, 0.0f);
        uA.h2[3] = pkrtz(0.0f, 0.0f);
        bxo = uo.v;
        bxA = uA.v;
    };
    loadx();                              // x_0
    cvtx();                               // bx = x_0
    f32x4 cr = {0.f, 0.f, 0.f, 0.f};      // c state: units u0..u0+3 of seq m

    // rotating output duty: wave w serves steps t with t&3 == w (row t-1)
    float* pOut = out + (size_t)((w + 3) & 3) * NSEQ + n0 + lane;

#pragma unroll 2
    for (int t = 0; t < T_STEPS; ++t) {
        const int cb  = t & 1;
        const int nb2 = cb ^ 1;
        // LDS-only barrier: x prefetch (vmcnt) may span it
        asm volatile("s_waitcnt lgkmcnt(0)\n\ts_barrier" ::: "memory");

        if (t + 1 < T_STEPS) loadx();     // issue x_{t+1} loads early (used at tail cvtx)

        // output duty (rotates): reduce prev step's 16 partials; overlaps h-read latency
        if (t > 0 && w == (t & 3) && lane < 16) {
            const float* pp = &partb[nb2][lane][0];
            f32x4 q0 = *(const f32x4*)pp;
            f32x4 q1 = *(const f32x4*)(pp + 4);
            f32x4 q2 = *(const f32x4*)(pp + 8);
            f32x4 q3 = *(const f32x4*)(pp + 12);
            f32x4 s4 = (q0 + q1) + (q2 + q3);
            *pOut = s4[0] + s4[1] + s4[2] + s4[3] + bd;
            pOut += 4 * NSEQ;
        }

        // B h-fragments: seq row m, phi-contiguous b128 slices (cols 0..63)
        const _Float16* bh = &Ahi[cb][m * HPAD];
        const _Float16* bl = &Alo[cb][m * HPAD];
        f16x8 bh0 = *(const f16x8*)(bh + 8 * g);          // k 0..31
        f16x8 bh1 = *(const f16x8*)(bh + 32 + 8 * g);     // k 32..63
        f16x8 bl0 = *(const f16x8*)(bl + 8 * g);
        f16x8 bl1 = *(const f16x8*)(bl + 32 + 8 * g);

        // 4 gate tiles; per gate: two independent 3-chains + vector add
        f32x4 acc[4];
        __builtin_amdgcn_s_setprio(1);
#pragma unroll
        for (int e = 0; e < 4; e++) {
            f32x4 z = {0.f, 0.f, 0.f, 0.f};
            f32x4 a1 = __builtin_amdgcn_mfma_f32_16x16x32_f16(Axo[e], bxo, z, 0, 0, 0);
            f32x4 a2 = __builtin_amdgcn_mfma_f32_16x16x32_f16(AxA[e], bxA, z, 0, 0, 0);
            a1 = __builtin_amdgcn_mfma_f32_16x16x32_f16(Ahh[e][0], bh0, a1, 0, 0, 0);
            a2 = __builtin_amdgcn_mfma_f32_16x16x32_f16(Ahh[e][1], bh1, a2, 0, 0, 0);
            a1 = __builtin_amdgcn_mfma_f32_16x16x32_f16(Ahh[e][0], bl0, a1, 0, 0, 0);
            a2 = __builtin_amdgcn_mfma_f32_16x16x32_f16(Ahh[e][1], bl1, a2, 0, 0, 0);
            acc[e] = a1 + a2;
        }
        __builtin_amdgcn_s_setprio(0);

        // cell update: 4 units (u0+r) of seq m; biases already in acc
        float h4[4];
#pragma unroll
        for (int r = 0; r < 4; r++) {
            float c = cr[r] * fsig(acc[2][r]) + fsig(acc[0][r]) * ftanh(acc[1][r]);
            cr[r] = c;
            h4[r] = ftanh(c) * fsig(acc[3][r]);
        }
        // pack hi/lo and write as two b64 (phi layout, 8B-aligned)
        F4 hi_;
        hi_.h2[0] = pkrtz(h4[0], h4[1]);
        hi_.h2[1] = pkrtz(h4[2], h4[3]);
        F4 lo_;
        lo_.h2[0] = pkrtz(h4[0] - (float)hi_.e[0], h4[1] - (float)hi_.e[1]);
        lo_.h2[1] = pkrtz(h4[2] - (float)hi_.e[2], h4[3] - (float)hi_.e[3]);
        *(f16x4*)(&Ahi[nb2][m * HPAD + sigb]) = hi_.v;
        *(f16x4*)(&Alo[nb2][m * HPAD + sigb]) = lo_.v;

        // decode partial: per-lane 4-FMA, direct LDS slot (no cross-lane ops)
        float p = h4[0] * wdv[0];
        p = fmaf(h4[1], wdv[1], p);
        p = fmaf(h4[2], wdv[2], p);
        p = fmaf(h4[3], wdv[3], p);
        partb[cb][m][4 * w + g] = p;

        // convert x_{t+1} at the tail (fills the write/pack shadow; loads issued at top)
        if (t + 1 < T_STEPS) cvtx();
    }

    // final row (t = T_STEPS-1 partials live in partb[1]); duty wave = 0
    __syncthreads();
    if (w == 0 && lane < 16) {
        const float* pp = &partb[1][lane][0];
        f32x4 q0 = *(const f32x4*)pp;
        f32x4 q1 = *(const f32x4*)(pp + 4);
        f32x4 q2 = *(const f32x4*)(pp + 8);
        f32x4 q3 = *(const f32x4*)(pp + 12);
        f32x4 s4 = (q0 + q1) + (q2 + q3);
        *pOut = s4[0] + s4[1] + s4[2] + s4[3] + bd;
    }
}

extern "C" void kernel_launch(void* const* d_in, const int* in_sizes, int n_in,
                              void* d_out, int out_size, void* d_ws, size_t ws_size,
                              hipStream_t stream) {
    (void)in_sizes; (void)n_in; (void)d_ws; (void)ws_size; (void)out_size;
    const float* obss    = (const float*)d_in[0];
    const float* actions = (const float*)d_in[1];
    const float* W       = (const float*)d_in[2];
    const float* b       = (const float*)d_in[3];
    const float* Wdec    = (const float*)d_in[4];
    const float* bdec    = (const float*)d_in[5];
    float* out = (float*)d_out;
    lstm_fused<<<dim3(NSEQ / NB), dim3(256), 0, stream>>>(obss, actions, W, b, Wdec, bdec, out);
}

// Round 14
// 195.959 us; speedup vs baseline: 1.7066x; 1.0091x over previous
//
#include <hip/hip_runtime.h>
#include <cstddef>

#define T_STEPS 256
#define OBS     32
#define ACTD    8
#define NB      16      // sequences per block (full N-dim of transposed MFMA)
#define HPAD    88      // h row stride in f16 (176 B)
#define NSEQ    4096

typedef _Float16 f16x8 __attribute__((ext_vector_type(8)));
typedef _Float16 f16x4 __attribute__((ext_vector_type(4)));
typedef _Float16 f16x2 __attribute__((ext_vector_type(2)));
typedef float    f32x4 __attribute__((ext_vector_type(4)));

union F8 { f16x8 v; _Float16 e[8]; f16x2 h2[4]; };
union F4 { f16x4 v; _Float16 e[4]; f16x2 h2[2]; };

#define LOG2E 1.44269504088896f

__device__ __forceinline__ float fsig(float x) {
    return __builtin_amdgcn_rcpf(1.0f + __builtin_amdgcn_exp2f(x * -LOG2E));
}
__device__ __forceinline__ float ftanh(float x) {
    return 2.0f * __builtin_amdgcn_rcpf(1.0f + __builtin_amdgcn_exp2f(x * (-2.0f * LOG2E))) - 1.0f;
}
__device__ __forceinline__ f16x2 pkrtz(float a, float b) {
    return __builtin_bit_cast(f16x2, __builtin_amdgcn_cvt_pkrtz(a, b));
}

__global__ __launch_bounds__(256)
void lstm_fused(const float* __restrict__ obss, const float* __restrict__ actions,
                const float* __restrict__ W, const float* __restrict__ b,
                const float* __restrict__ Wdec, const float* __restrict__ bdec_p,
                float* __restrict__ out)
{
    // Transposed GEMM: D[gate-col][seq] = W^T (A, static regs) x [h|x]^T (B).
    // h LDS: row = seq, col = phi(unit); phi(u)=(u&3)+4*((u>>4)&1)+8*((u>>2)&3)+32*(u>>5)
    // Biases ride the MFMA through the act-tile's k=8 slot (B=1.0 there).
    // x-side MFMAs are precomputed at the previous step's tail (h-independent).
    __shared__ __align__(16) _Float16 Ahi[2][NB * HPAD];
    __shared__ __align__(16) _Float16 Alo[2][NB * HPAD];
    __shared__ __align__(16) float partb[2][16][20];   // [buf][seq][16 partials (4w+g)]

    const int tid  = threadIdx.x;
    const int w    = tid >> 6;            // wave 0..3
    const int lane = tid & 63;
    const int g    = lane >> 4;           // k-group / D-row-group
    const int m    = lane & 15;           // seq (B col / D col); A row = gate-col 64e+16w+m
    const int n0   = blockIdx.x * NB;
    const int u0   = 16 * w + 4 * g;      // first of 4 units this lane updates
    const int sigb = 32 * (w >> 1) + 8 * g + 4 * (w & 1);  // = phi(u0), 8B-aligned

    // ---- one-time: W^T fragments as A operands (plain f16; h hi/lo is B-side) ----
    f16x8 Ahh[4][2], Axo[4], AxA[4];
    {
        const float* Wc = W + 16 * w + m;     // tile e -> gate-col 64e + 16w + m
#pragma unroll
        for (int e = 0; e < 4; e++) {
#pragma unroll
            for (int c = 0; c < 2; c++) {
                F8 hi;
#pragma unroll
                for (int i = 0; i < 8; i++) {
                    int k = 32 * c + 16 * (i >> 2) + 4 * g + (i & 3);  // h-k 0..63
                    hi.e[i] = (_Float16)Wc[(40 + k) * 256 + 64 * e];
                }
                Ahh[e][c] = hi.v;
            }
            F8 xo, xA;
            // bias for this lane's A-row (gate-col 64e+16w+m); forget gate +1.0
            float bv = b[64 * e + 16 * w + m] + (e == 2 ? 1.0f : 0.0f);
#pragma unroll
            for (int i = 0; i < 8; i++) {
                int d = 16 * (i >> 2) + 4 * g + (i & 3);               // 0..31
                xo.e[i] = (_Float16)Wc[d * 256 + 64 * e];
                xA.e[i] = (d < ACTD) ? (_Float16)Wc[(OBS + d) * 256 + 64 * e]
                        : (d == 8)   ? (_Float16)bv
                                     : (_Float16)0.0f;                 // act tile, K32-padded
            }
            Axo[e] = xo.v;
            AxA[e] = xA.v;
        }
    }
    f32x4 wdv = *(const f32x4*)&Wdec[u0];
    const float bd = bdec_p[0];

    for (int i = tid; i < 2 * NB * HPAD; i += 256) {
        (&Ahi[0][0])[i] = (_Float16)0.0f;
        (&Alo[0][0])[i] = (_Float16)0.0f;
    }
    __syncthreads();

    // per-lane x: seq m, dim-slice by g; running pointers.
    const float* pO = obss    + ((size_t)(n0 + m) * T_STEPS) * OBS  + 4 * g;
    const float* pA = actions + ((size_t)(n0 + m) * T_STEPS) * ACTD + 4 * g;
    f32x4 xo0 = {0,0,0,0}, xo1 = {0,0,0,0}, xa = {0,0,0,0};
    auto loadx = [&]() {
        xo0 = *(const f32x4*)pO;
        xo1 = *(const f32x4*)(pO + 16);
        pO += OBS;
        if (g < 2) { xa = *(const f32x4*)pA; pA += ACTD; }
    };
    f16x8 bxo, bxA;
    auto cvtx = [&]() {
        F8 uo;
        uo.h2[0] = pkrtz(xo0[0], xo0[1]);
        uo.h2[1] = pkrtz(xo0[2], xo0[3]);
        uo.h2[2] = pkrtz(xo1[0], xo1[1]);
        uo.h2[3] = pkrtz(xo1[2], xo1[3]);
        F8 uA;
        uA.h2[0] = pkrtz(g == 2 ? 1.0f : xa[0], xa[1]);   // k=8 slot carries 1.0 (bias row)
        uA.h2[1] = pkrtz(xa[2], xa[3]);
        uA.h2[2] = pkrtz(0.0f, 0.0f);
        uA.h2[3] = pkrtz(0.0f, 0.0f);
        bxo = uo.v;
        bxA = uA.v;
    };
    // precomputed x-side partial accumulators (h-independent MFMA products)
    f32x4 p1[4], p2[4];
    auto pmm = [&]() {
        const f32x4 z = {0.f, 0.f, 0.f, 0.f};
#pragma unroll
        for (int e = 0; e < 4; e++) {
            p1[e] = __builtin_amdgcn_mfma_f32_16x16x32_f16(Axo[e], bxo, z, 0, 0, 0);
            p2[e] = __builtin_amdgcn_mfma_f32_16x16x32_f16(AxA[e], bxA, z, 0, 0, 0);
        }
    };
    loadx();                              // x_0
    cvtx();
    pmm();                                // p = x_0 products
    f32x4 cr = {0.f, 0.f, 0.f, 0.f};      // c state: units u0..u0+3 of seq m

    // rotating output duty: wave w serves steps t with t&3 == w (row t-1)
    float* pOut = out + (size_t)((w + 3) & 3) * NSEQ + n0 + lane;

#pragma unroll 2
    for (int t = 0; t < T_STEPS; ++t) {
        const int cb  = t & 1;
        const int nb2 = cb ^ 1;
        // LDS-only barrier: x prefetch (vmcnt) may span it
        asm volatile("s_waitcnt lgkmcnt(0)\n\ts_barrier" ::: "memory");

        if (t + 1 < T_STEPS) loadx();     // issue x_{t+1} loads (consumed at tail cvtx)

        // output duty (rotates): reduce prev step's 16 partials; overlaps h-read latency
        if (t > 0 && w == (t & 3) && lane < 16) {
            const float* pp = &partb[nb2][lane][0];
            f32x4 q0 = *(const f32x4*)pp;
            f32x4 q1 = *(const f32x4*)(pp + 4);
            f32x4 q2 = *(const f32x4*)(pp + 8);
            f32x4 q3 = *(const f32x4*)(pp + 12);
            f32x4 s4 = (q0 + q1) + (q2 + q3);
            *pOut = s4[0] + s4[1] + s4[2] + s4[3] + bd;
            pOut += 4 * NSEQ;
        }

        // B h-fragments: seq row m, phi-contiguous b128 slices (cols 0..63)
        const _Float16* bh = &Ahi[cb][m * HPAD];
        const _Float16* bl = &Alo[cb][m * HPAD];
        f16x8 bh0 = *(const f16x8*)(bh + 8 * g);          // k 0..31
        f16x8 bh1 = *(const f16x8*)(bh + 32 + 8 * g);     // k 32..63
        f16x8 bl0 = *(const f16x8*)(bl + 8 * g);
        f16x8 bl1 = *(const f16x8*)(bl + 32 + 8 * g);

        // 4 gate tiles; h-chain depth 2, starting from precomputed x partials
        f32x4 acc[4];
        __builtin_amdgcn_s_setprio(1);
#pragma unroll
        for (int e = 0; e < 4; e++) {
            f32x4 a1 = __builtin_amdgcn_mfma_f32_16x16x32_f16(Ahh[e][0], bh0, p1[e], 0, 0, 0);
            f32x4 a2 = __builtin_amdgcn_mfma_f32_16x16x32_f16(Ahh[e][1], bh1, p2[e], 0, 0, 0);
            a1 = __builtin_amdgcn_mfma_f32_16x16x32_f16(Ahh[e][0], bl0, a1, 0, 0, 0);
            a2 = __builtin_amdgcn_mfma_f32_16x16x32_f16(Ahh[e][1], bl1, a2, 0, 0, 0);
            acc[e] = a1 + a2;
        }
        __builtin_amdgcn_s_setprio(0);

        // cell update: 4 units (u0+r) of seq m; biases already in acc
        float h4[4];
#pragma unroll
        for (int r = 0; r < 4; r++) {
            float c = cr[r] * fsig(acc[2][r]) + fsig(acc[0][r]) * ftanh(acc[1][r]);
            cr[r] = c;
            h4[r] = ftanh(c) * fsig(acc[3][r]);
        }
        // pack hi/lo and write as two b64 (phi layout, 8B-aligned)
        F4 hi_;
        hi_.h2[0] = pkrtz(h4[0], h4[1]);
        hi_.h2[1] = pkrtz(h4[2], h4[3]);
        F4 lo_;
        lo_.h2[0] = pkrtz(h4[0] - (float)hi_.e[0], h4[1] - (float)hi_.e[1]);
        lo_.h2[1] = pkrtz(h4[2] - (float)hi_.e[2], h4[3] - (float)hi_.e[3]);
        *(f16x4*)(&Ahi[nb2][m * HPAD + sigb]) = hi_.v;
        *(f16x4*)(&Alo[nb2][m * HPAD + sigb]) = lo_.v;

        // decode partial: per-lane 4-FMA, direct LDS slot (no cross-lane ops)
        float p = h4[0] * wdv[0];
        p = fmaf(h4[1], wdv[1], p);
        p = fmaf(h4[2], wdv[2], p);
        p = fmaf(h4[3], wdv[3], p);
        partb[cb][m][4 * w + g] = p;

        // tail: convert x_{t+1} and precompute its x-side MFMAs (fills write shadow)
        if (t + 1 < T_STEPS) {
            cvtx();
            __builtin_amdgcn_s_setprio(1);
            pmm();
            __builtin_amdgcn_s_setprio(0);
        }
    }

    // final row (t = T_STEPS-1 partials live in partb[1]); duty wave = 0
    __syncthreads();
    if (w == 0 && lane < 16) {
        const float* pp = &partb[1][lane][0];
        f32x4 q0 = *(const f32x4*)pp;
        f32x4 q1 = *(const f32x4*)(pp + 4);
        f32x4 q2 = *(const f32x4*)(pp + 8);
        f32x4 q3 = *(const f32x4*)(pp + 12);
        f32x4 s4 = (q0 + q1) + (q2 + q3);
        *pOut = s4[0] + s4[1] + s4[2] + s4[3] + bd;
    }
}

extern "C" void kernel_launch(void* const* d_in, const int* in_sizes, int n_in,
                              void* d_out, int out_size, void* d_ws, size_t ws_size,
                              hipStream_t stream) {
    (void)in_sizes; (void)n_in; (void)d_ws; (void)ws_size; (void)out_size;
    const float* obss    = (const float*)d_in[0];
    const float* actions = (const float*)d_in[1];
    const float* W       = (const float*)d_in[2];
    const float* b       = (const float*)d_in[3];
    const float* Wdec    = (const float*)d_in[4];
    const float* bdec    = (const float*)d_in[5];
    float* out = (float*)d_out;
    lstm_fused<<<dim3(NSEQ / NB), dim3(256), 0, stream>>>(obss, actions, W, b, Wdec, bdec, out);
}

// Round 15
// 189.539 us; speedup vs baseline: 1.7644x; 1.0339x over previous
//
#include <hip/hip_runtime.h>
#include <cstddef>

#define T_STEPS 256
#define OBS     32
#define ACTD    8
#define NB      16      // sequences per block (full N-dim of transposed MFMA)
#define HPAD    88      // h row stride in f16 (176 B)
#define NSEQ    4096

typedef _Float16 f16x8 __attribute__((ext_vector_type(8)));
typedef _Float16 f16x4 __attribute__((ext_vector_type(4)));
typedef _Float16 f16x2 __attribute__((ext_vector_type(2)));
typedef float    f32x4 __attribute__((ext_vector_type(4)));

union F8 { f16x8 v; _Float16 e[8]; f16x2 h2[4]; };
union F4 { f16x4 v; _Float16 e[4]; f16x2 h2[2]; };

#define LOG2E 1.44269504088896f

__device__ __forceinline__ float fsig(float x) {
    return __builtin_amdgcn_rcpf(1.0f + __builtin_amdgcn_exp2f(x * -LOG2E));
}
__device__ __forceinline__ f16x2 pkrtz(float a, float b) {
    return __builtin_bit_cast(f16x2, __builtin_amdgcn_cvt_pkrtz(a, b));
}

__global__ __launch_bounds__(256)
void lstm_fused(const float* __restrict__ obss, const float* __restrict__ actions,
                const float* __restrict__ W, const float* __restrict__ b,
                const float* __restrict__ Wdec, const float* __restrict__ bdec_p,
                float* __restrict__ out)
{
    // Transposed GEMM: D[gate-col][seq] = W^T (A, static regs) x [h|x]^T (B).
    // h LDS (single f16): row = seq, col = phi(unit);
    // phi(u)=(u&3)+4*((u>>4)&1)+8*((u>>2)&3)+32*(u>>5)
    // Biases ride the MFMA through the act-tile's k=8 slot (B=1.0 there).
    // x-side MFMAs precomputed at the previous step's tail (h-independent).
    __shared__ __align__(16) _Float16 Ah[2][NB * HPAD];
    __shared__ __align__(16) float partb[2][16][20];   // [buf][seq][16 partials (4w+g)]

    const int tid  = threadIdx.x;
    const int w    = tid >> 6;            // wave 0..3
    const int lane = tid & 63;
    const int g    = lane >> 4;           // k-group / D-row-group
    const int m    = lane & 15;           // seq (B col / D col); A row = gate-col 64e+16w+m
    const int n0   = blockIdx.x * NB;
    const int u0   = 16 * w + 4 * g;      // first of 4 units this lane updates
    const int sigb = 32 * (w >> 1) + 8 * g + 4 * (w & 1);  // = phi(u0), 8B-aligned

    // ---- one-time: W^T fragments as A operands ----
    f16x8 Ahh[4][2], Axo[4], AxA[4];
    {
        const float* Wc = W + 16 * w + m;     // tile e -> gate-col 64e + 16w + m
#pragma unroll
        for (int e = 0; e < 4; e++) {
#pragma unroll
            for (int c = 0; c < 2; c++) {
                F8 hi;
#pragma unroll
                for (int i = 0; i < 8; i++) {
                    int k = 32 * c + 16 * (i >> 2) + 4 * g + (i & 3);  // h-k 0..63
                    hi.e[i] = (_Float16)Wc[(40 + k) * 256 + 64 * e];
                }
                Ahh[e][c] = hi.v;
            }
            F8 xo, xA;
            // bias for this lane's A-row (gate-col 64e+16w+m); forget gate +1.0
            float bv = b[64 * e + 16 * w + m] + (e == 2 ? 1.0f : 0.0f);
#pragma unroll
            for (int i = 0; i < 8; i++) {
                int d = 16 * (i >> 2) + 4 * g + (i & 3);               // 0..31
                xo.e[i] = (_Float16)Wc[d * 256 + 64 * e];
                xA.e[i] = (d < ACTD) ? (_Float16)Wc[(OBS + d) * 256 + 64 * e]
                        : (d == 8)   ? (_Float16)bv
                                     : (_Float16)0.0f;                 // act tile, K32-padded
            }
            Axo[e] = xo.v;
            AxA[e] = xA.v;
        }
    }
    f32x4 wdv = *(const f32x4*)&Wdec[u0];
    const float bd = bdec_p[0];

    for (int i = tid; i < 2 * NB * HPAD; i += 256)
        (&Ah[0][0])[i] = (_Float16)0.0f;
    __syncthreads();

    // per-lane x: seq m, dim-slice by g; running pointers.
    const float* pO = obss    + ((size_t)(n0 + m) * T_STEPS) * OBS  + 4 * g;
    const float* pA = actions + ((size_t)(n0 + m) * T_STEPS) * ACTD + 4 * g;
    f32x4 xo0 = {0,0,0,0}, xo1 = {0,0,0,0}, xa = {0,0,0,0};
    auto loadx = [&]() {
        xo0 = *(const f32x4*)pO;
        xo1 = *(const f32x4*)(pO + 16);
        pO += OBS;
        if (g < 2) { xa = *(const f32x4*)pA; pA += ACTD; }
    };
    f16x8 bxo, bxA;
    auto cvtx = [&]() {
        F8 uo;
        uo.h2[0] = pkrtz(xo0[0], xo0[1]);
        uo.h2[1] = pkrtz(xo0[2], xo0[3]);
        uo.h2[2] = pkrtz(xo1[0], xo1[1]);
        uo.h2[3] = pkrtz(xo1[2], xo1[3]);
        F8 uA;
        uA.h2[0] = pkrtz(g == 2 ? 1.0f : xa[0], xa[1]);   // k=8 slot carries 1.0 (bias row)
        uA.h2[1] = pkrtz(xa[2], xa[3]);
        uA.h2[2] = pkrtz(0.0f, 0.0f);
        uA.h2[3] = pkrtz(0.0f, 0.0f);
        bxo = uo.v;
        bxA = uA.v;
    };
    // precomputed x-side partial accumulators (h-independent MFMA products)
    f32x4 p1[4], p2[4];
    auto pmm = [&]() {
        const f32x4 z = {0.f, 0.f, 0.f, 0.f};
#pragma unroll
        for (int e = 0; e < 4; e++) {
            p1[e] = __builtin_amdgcn_mfma_f32_16x16x32_f16(Axo[e], bxo, z, 0, 0, 0);
            p2[e] = __builtin_amdgcn_mfma_f32_16x16x32_f16(AxA[e], bxA, z, 0, 0, 0);
        }
    };
    loadx();                              // x_0
    cvtx();
    pmm();                                // p = x_0 products
    f32x4 cr = {0.f, 0.f, 0.f, 0.f};      // c state: units u0..u0+3 of seq m

    // rotating output duty: wave w serves steps t with t&3 == w (row t-1)
    float* pOut = out + (size_t)((w + 3) & 3) * NSEQ + n0 + lane;

#pragma unroll 2
    for (int t = 0; t < T_STEPS; ++t) {
        const int cb  = t & 1;
        const int nb2 = cb ^ 1;
        // LDS-only barrier: x prefetch (vmcnt) may span it
        asm volatile("s_waitcnt lgkmcnt(0)\n\ts_barrier" ::: "memory");

        if (t + 1 < T_STEPS) loadx();     // issue x_{t+1} loads (consumed at tail cvtx)

        // output duty (rotates): reduce prev step's 16 partials; overlaps h-read latency
        if (t > 0 && w == (t & 3) && lane < 16) {
            const float* pp = &partb[nb2][lane][0];
            f32x4 q0 = *(const f32x4*)pp;
            f32x4 q1 = *(const f32x4*)(pp + 4);
            f32x4 q2 = *(const f32x4*)(pp + 8);
            f32x4 q3 = *(const f32x4*)(pp + 12);
            f32x4 s4 = (q0 + q1) + (q2 + q3);
            *pOut = s4[0] + s4[1] + s4[2] + s4[3] + bd;
            pOut += 4 * NSEQ;
        }

        // B h-fragments: seq row m, phi-contiguous b128 slices (cols 0..63)
        const _Float16* bh = &Ah[cb][m * HPAD];
        f16x8 bh0 = *(const f16x8*)(bh + 8 * g);          // k 0..31
        f16x8 bh1 = *(const f16x8*)(bh + 32 + 8 * g);     // k 32..63

        // 4 gate tiles; h-chain depth 1, starting from precomputed x partials
        f32x4 acc[4];
        __builtin_amdgcn_s_setprio(1);
#pragma unroll
        for (int e = 0; e < 4; e++) {
            f32x4 a1 = __builtin_amdgcn_mfma_f32_16x16x32_f16(Ahh[e][0], bh0, p1[e], 0, 0, 0);
            f32x4 a2 = __builtin_amdgcn_mfma_f32_16x16x32_f16(Ahh[e][1], bh1, p2[e], 0, 0, 0);
            acc[e] = a1 + a2;
        }
        __builtin_amdgcn_s_setprio(0);

        // cell update: 4 units (u0+r) of seq m; fused-rcp activations (8 trans/unit)
        float h4[4];
#pragma unroll
        for (int r = 0; r < 4; r++) {
            float sf = fsig(acc[2][r]);                              // forget gate
            // sig(i)*tanh(j) = (B-2) / (A*B), A=1+e^-i, B=1+e^-2j
            float ei = __builtin_amdgcn_exp2f(acc[0][r] * -LOG2E);
            float ej = __builtin_amdgcn_exp2f(acc[1][r] * (-2.0f * LOG2E));
            float A = 1.0f + ei, B = 1.0f + ej;
            float prod = (B - 2.0f) * __builtin_amdgcn_rcpf(A * B);
            float c = cr[r] * sf + prod;
            cr[r] = c;
            // tanh(c)*sig(o) = (D-2) / (D*E), D=1+e^-2c, E=1+e^-o
            float ec = __builtin_amdgcn_exp2f(c * (-2.0f * LOG2E));
            float eo = __builtin_amdgcn_exp2f(acc[3][r] * -LOG2E);
            float D = 1.0f + ec, E = 1.0f + eo;
            h4[r] = (D - 2.0f) * __builtin_amdgcn_rcpf(D * E);
        }
        // pack and write h as one b64 (phi layout, 8B-aligned)
        F4 hi_;
        hi_.h2[0] = pkrtz(h4[0], h4[1]);
        hi_.h2[1] = pkrtz(h4[2], h4[3]);
        *(f16x4*)(&Ah[nb2][m * HPAD + sigb]) = hi_.v;

        // decode partial: per-lane 4-FMA, direct LDS slot (no cross-lane ops)
        float p = h4[0] * wdv[0];
        p = fmaf(h4[1], wdv[1], p);
        p = fmaf(h4[2], wdv[2], p);
        p = fmaf(h4[3], wdv[3], p);
        partb[cb][m][4 * w + g] = p;

        // tail: convert x_{t+1} and precompute its x-side MFMAs (fills write shadow)
        if (t + 1 < T_STEPS) {
            cvtx();
            __builtin_amdgcn_s_setprio(1);
            pmm();
            __builtin_amdgcn_s_setprio(0);
        }
    }

    // final row (t = T_STEPS-1 partials live in partb[1]); duty wave = 0
    __syncthreads();
    if (w == 0 && lane < 16) {
        const float* pp = &partb[1][lane][0];
        f32x4 q0 = *(const f32x4*)pp;
        f32x4 q1 = *(const f32x4*)(pp + 4);
        f32x4 q2 = *(const f32x4*)(pp + 8);
        f32x4 q3 = *(const f32x4*)(pp + 12);
        f32x4 s4 = (q0 + q1) + (q2 + q3);
        *pOut = s4[0] + s4[1] + s4[2] + s4[3] + bd;
    }
}

extern "C" void kernel_launch(void* const* d_in, const int* in_sizes, int n_in,
                              void* d_out, int out_size, void* d_ws, size_t ws_size,
                              hipStream_t stream) {
    (void)in_sizes; (void)n_in; (void)d_ws; (void)ws_size; (void)out_size;
    const float* obss    = (const float*)d_in[0];
    const float* actions = (const float*)d_in[1];
    const float* W       = (const float*)d_in[2];
    const float* b       = (const float*)d_in[3];
    const float* Wdec    = (const float*)d_in[4];
    const float* bdec    = (const float*)d_in[5];
    float* out = (float*)d_out;
    lstm_fused<<<dim3(NSEQ / NB), dim3(256), 0, stream>>>(obss, actions, W, b, Wdec, bdec, out);
}

// Round 16
// 145.748 us; speedup vs baseline: 2.2945x; 1.3005x over previous
//
#include <hip/hip_runtime.h>
#include <cstddef>

#define T_STEPS 256
#define OBS     32
#define ACTD    8
#define NB      16      // sequences per block (full N-dim of transposed MFMA)
#define HPAD    88      // h row stride in f16 (176 B)
#define NSEQ    4096

typedef _Float16 f16x8 __attribute__((ext_vector_type(8)));
typedef _Float16 f16x4 __attribute__((ext_vector_type(4)));
typedef _Float16 f16x2 __attribute__((ext_vector_type(2)));
typedef float    f32x4 __attribute__((ext_vector_type(4)));

union F8 { f16x8 v; _Float16 e[8]; f16x2 h2[4]; };
union F4 { f16x4 v; _Float16 e[4]; f16x2 h2[2]; };

#define LOG2E 1.44269504088896f

__device__ __forceinline__ float fsig(float x) {
    return __builtin_amdgcn_rcpf(1.0f + __builtin_amdgcn_exp2f(x * -LOG2E));
}
__device__ __forceinline__ f16x2 pkrtz(float a, float b) {
    return __builtin_bit_cast(f16x2, __builtin_amdgcn_cvt_pkrtz(a, b));
}

__global__ __launch_bounds__(512)
void lstm_fused(const float* __restrict__ obss, const float* __restrict__ actions,
                const float* __restrict__ W, const float* __restrict__ b,
                const float* __restrict__ Wdec, const float* __restrict__ bdec_p,
                float* __restrict__ out)
{
    // Producer/consumer wave split, transposed GEMM D[gate-col][seq]:
    //   A-waves (0-3): h-MFMAs (depth 2 from pbuf) + cell update + h write.
    //   B-waves (4-7): x loads/cvt, x-side MFMAs -> pbuf (1 step ahead), output duty.
    // h LDS: row = seq, col = phi(unit); phi(u)=(u&3)+4*((u>>4)&1)+8*((u>>2)&3)+32*(u>>5)
    // Biases ride B's act-tile k=8 slot (B-operand carries 1.0 there).
    __shared__ __align__(16) _Float16 Ah[2][NB * HPAD];
    __shared__ __align__(16) float partb[2][16][20];          // [buf][seq][16 partials]
    __shared__ __align__(16) float pbuf[2][4][4][4][16][4];   // [buf][wave][e][g][m][r]

    const int tid  = threadIdx.x;
    const int w8   = tid >> 6;            // physical wave 0..7
    const int w    = w8 & 3;              // unit-slice 0..3 (A and B pair on same w)
    const bool isA = w8 < 4;
    const int lane = tid & 63;
    const int g    = lane >> 4;           // k-group / D-row-group
    const int m    = lane & 15;           // seq (B col / D col)
    const int n0   = blockIdx.x * NB;
    const int u0   = 16 * w + 4 * g;      // first of 4 units an A-lane updates
    const int sigb = 32 * (w >> 1) + 8 * g + 4 * (w & 1);  // = phi(u0), 8B-aligned

    // ---- W fragments: A loads h-side; B loads x-side (+bias in k=8 slot) ----
    f16x8 Ahh[4][2];                      // A-waves only
    f16x8 Axo[4], AxA[4];                 // B-waves only
    f32x4 wdv = {0.f, 0.f, 0.f, 0.f};
    {
        const float* Wc = W + 16 * w + m;     // tile e -> gate-col 64e + 16w + m
        if (isA) {
#pragma unroll
            for (int e = 0; e < 4; e++) {
#pragma unroll
                for (int c = 0; c < 2; c++) {
                    F8 hi;
#pragma unroll
                    for (int i = 0; i < 8; i++) {
                        int k = 32 * c + 16 * (i >> 2) + 4 * g + (i & 3);  // h-k 0..63
                        hi.e[i] = (_Float16)Wc[(40 + k) * 256 + 64 * e];
                    }
                    Ahh[e][c] = hi.v;
                }
            }
            wdv = *(const f32x4*)&Wdec[u0];
        } else {
#pragma unroll
            for (int e = 0; e < 4; e++) {
                F8 xo, xA;
                float bv = b[64 * e + 16 * w + m] + (e == 2 ? 1.0f : 0.0f);
#pragma unroll
                for (int i = 0; i < 8; i++) {
                    int d = 16 * (i >> 2) + 4 * g + (i & 3);               // 0..31
                    xo.e[i] = (_Float16)Wc[d * 256 + 64 * e];
                    xA.e[i] = (d < ACTD) ? (_Float16)Wc[(OBS + d) * 256 + 64 * e]
                            : (d == 8)   ? (_Float16)bv
                                         : (_Float16)0.0f;
                }
                Axo[e] = xo.v;
                AxA[e] = xA.v;
            }
        }
    }
    const float bd = bdec_p[0];

    for (int i = tid; i < 2 * NB * HPAD; i += 512)
        (&Ah[0][0])[i] = (_Float16)0.0f;

    // ---- B-wave x pipeline state ----
    const float* pO = obss    + ((size_t)(n0 + m) * T_STEPS) * OBS  + 4 * g;
    const float* pA = actions + ((size_t)(n0 + m) * T_STEPS) * ACTD + 4 * g;
    f32x4 xo0 = {0,0,0,0}, xo1 = {0,0,0,0}, xa = {0,0,0,0};
    auto loadx = [&]() {
        xo0 = *(const f32x4*)pO;
        xo1 = *(const f32x4*)(pO + 16);
        pO += OBS;
        if (g < 2) { xa = *(const f32x4*)pA; pA += ACTD; }
    };
    f16x8 bxo, bxA;
    auto cvtx = [&]() {
        F8 uo;
        uo.h2[0] = pkrtz(xo0[0], xo0[1]);
        uo.h2[1] = pkrtz(xo0[2], xo0[3]);
        uo.h2[2] = pkrtz(xo1[0], xo1[1]);
        uo.h2[3] = pkrtz(xo1[2], xo1[3]);
        F8 uA;
        uA.h2[0] = pkrtz(g == 2 ? 1.0f : xa[0], xa[1]);   // k=8 slot carries 1.0
        uA.h2[1] = pkrtz(xa[2], xa[3]);
        uA.h2[2] = pkrtz(0.0f, 0.0f);
        uA.h2[3] = pkrtz(0.0f, 0.0f);
        bxo = uo.v;
        bxA = uA.v;
    };
    auto pmm_store = [&](int buf) {
        const f32x4 z = {0.f, 0.f, 0.f, 0.f};
#pragma unroll
        for (int e = 0; e < 4; e++) {
            f32x4 pc = __builtin_amdgcn_mfma_f32_16x16x32_f16(Axo[e], bxo, z, 0, 0, 0);
            pc = __builtin_amdgcn_mfma_f32_16x16x32_f16(AxA[e], bxA, pc, 0, 0, 0);
            *(f32x4*)&pbuf[buf][w][e][g][m][0] = pc;
        }
    };

    if (!isA) {
        loadx();          // x_0
        cvtx();
        pmm_store(0);     // p for t=0
        loadx();          // x_1 (in flight; cvt'd at t=0)
    }
    f32x4 cr = {0.f, 0.f, 0.f, 0.f};      // A: c state, units u0..u0+3 of seq m
    // B: rotating output duty, wave w serves steps t with t&3 == w (row t-1)
    float* pOut = out + (size_t)((w + 3) & 3) * NSEQ + n0 + lane;

    __syncthreads();
    if (isA) __builtin_amdgcn_s_setprio(1);   // consumer wave wins issue arbitration

#pragma unroll 2
    for (int t = 0; t < T_STEPS; ++t) {
        const int cb  = t & 1;
        const int nb2 = cb ^ 1;
        // LDS-only barrier: B's global x loads may span it
        asm volatile("s_waitcnt lgkmcnt(0)\n\ts_barrier" ::: "memory");

        if (isA) {
            // h B-fragments: seq row m, phi-contiguous b128 slices (cols 0..63)
            const _Float16* bh = &Ah[cb][m * HPAD];
            f16x8 bh0 = *(const f16x8*)(bh + 8 * g);          // k 0..31
            f16x8 bh1 = *(const f16x8*)(bh + 32 + 8 * g);     // k 32..63

            // 4 gate tiles: depth-2 h-chain from B-produced x partial
            f32x4 acc[4];
#pragma unroll
            for (int e = 0; e < 4; e++) {
                f32x4 pe = *(const f32x4*)&pbuf[cb][w][e][g][m][0];
                f32x4 a = __builtin_amdgcn_mfma_f32_16x16x32_f16(Ahh[e][0], bh0, pe, 0, 0, 0);
                a = __builtin_amdgcn_mfma_f32_16x16x32_f16(Ahh[e][1], bh1, a, 0, 0, 0);
                acc[e] = a;
            }

            // cell update: 4 units (u0+r) of seq m; fused-rcp activations
            float h4[4];
#pragma unroll
            for (int r = 0; r < 4; r++) {
                float sf = fsig(acc[2][r]);                          // forget gate
                float ei = __builtin_amdgcn_exp2f(acc[0][r] * -LOG2E);
                float ej = __builtin_amdgcn_exp2f(acc[1][r] * (-2.0f * LOG2E));
                float A = 1.0f + ei, B = 1.0f + ej;
                float prod = (B - 2.0f) * __builtin_amdgcn_rcpf(A * B);
                float c = cr[r] * sf + prod;
                cr[r] = c;
                float ec = __builtin_amdgcn_exp2f(c * (-2.0f * LOG2E));
                float eo = __builtin_amdgcn_exp2f(acc[3][r] * -LOG2E);
                float D = 1.0f + ec, E = 1.0f + eo;
                h4[r] = (D - 2.0f) * __builtin_amdgcn_rcpf(D * E);
            }
            // pack and write h as one b64 (phi layout)
            F4 hi_;
            hi_.h2[0] = pkrtz(h4[0], h4[1]);
            hi_.h2[1] = pkrtz(h4[2], h4[3]);
            *(f16x4*)(&Ah[nb2][m * HPAD + sigb]) = hi_.v;

            // decode partial: per-lane 4-FMA, direct LDS slot
            float p = h4[0] * wdv[0];
            p = fmaf(h4[1], wdv[1], p);
            p = fmaf(h4[2], wdv[2], p);
            p = fmaf(h4[3], wdv[3], p);
            partb[cb][m][4 * w + g] = p;
        } else {
            // producer: convert x_{t+1} (loaded last step) and stage its x-MFMA
            if (t + 1 < T_STEPS) {
                cvtx();
                pmm_store(nb2);           // pbuf[(t+1)&1]
            }
            if (t + 2 < T_STEPS) loadx(); // issue x_{t+2} loads (span next barrier)

            // output duty (rotates): reduce prev step's 16 partials, store row t-1
            if (t > 0 && w == (t & 3) && lane < 16) {
                const float* pp = &partb[nb2][lane][0];
                f32x4 q0 = *(const f32x4*)pp;
                f32x4 q1 = *(const f32x4*)(pp + 4);
                f32x4 q2 = *(const f32x4*)(pp + 8);
                f32x4 q3 = *(const f32x4*)(pp + 12);
                f32x4 s4 = (q0 + q1) + (q2 + q3);
                *pOut = s4[0] + s4[1] + s4[2] + s4[3] + bd;
                pOut += 4 * NSEQ;
            }
        }
    }
    if (isA) __builtin_amdgcn_s_setprio(0);

    // final row (t = T_STEPS-1 partials live in partb[1]); B-wave 0 serves it
    __syncthreads();
    if (!isA && w == 0 && lane < 16) {
        const float* pp = &partb[1][lane][0];
        f32x4 q0 = *(const f32x4*)pp;
        f32x4 q1 = *(const f32x4*)(pp + 4);
        f32x4 q2 = *(const f32x4*)(pp + 8);
        f32x4 q3 = *(const f32x4*)(pp + 12);
        f32x4 s4 = (q0 + q1) + (q2 + q3);
        *pOut = s4[0] + s4[1] + s4[2] + s4[3] + bd;
    }
}

extern "C" void kernel_launch(void* const* d_in, const int* in_sizes, int n_in,
                              void* d_out, int out_size, void* d_ws, size_t ws_size,
                              hipStream_t stream) {
    (void)in_sizes; (void)n_in; (void)d_ws; (void)ws_size; (void)out_size;
    const float* obss    = (const float*)d_in[0];
    const float* actions = (const float*)d_in[1];
    const float* W       = (const float*)d_in[2];
    const float* b       = (const float*)d_in[3];
    const float* Wdec    = (const float*)d_in[4];
    const float* bdec    = (const float*)d_in[5];
    float* out = (float*)d_out;
    lstm_fused<<<dim3(NSEQ / NB), dim3(512), 0, stream>>>(obss, actions, W, b, Wdec, bdec, out);
}

// Round 17
// 133.828 us; speedup vs baseline: 2.4989x; 1.0891x over previous
//
#include <hip/hip_runtime.h>
#include <cstddef>

#define T_STEPS 256
#define OBS     32
#define ACTD    8
#define NB      16      // sequences per block (full N-dim of transposed MFMA)
#define HPAD2   152     // Bop row stride in f16 (304 B; 76 dw == 12 mod 32)
#define NSEQ    4096

typedef _Float16 f16x8 __attribute__((ext_vector_type(8)));
typedef _Float16 f16x4 __attribute__((ext_vector_type(4)));
typedef _Float16 f16x2 __attribute__((ext_vector_type(2)));
typedef float    f32x4 __attribute__((ext_vector_type(4)));

union F8 { f16x8 v; _Float16 e[8]; f16x2 h2[4]; };
union F4 { f16x4 v; _Float16 e[4]; f16x2 h2[2]; };

#define LOG2E 1.44269504088896f

__device__ __forceinline__ f16x2 pkrtz(float a, float b) {
    return __builtin_bit_cast(f16x2, __builtin_amdgcn_cvt_pkrtz(a, b));
}

__global__ __launch_bounds__(512)
void lstm_fused(const float* __restrict__ obss, const float* __restrict__ actions,
                const float* __restrict__ W, const float* __restrict__ b,
                const float* __restrict__ Wdec, const float* __restrict__ bdec_p,
                float* __restrict__ out)
{
    // Unified B-operand LDS: per seq row, cols 0..63 = phi(h) (A writes),
    // cols 64..103 = pi-permuted x (B writes f16 frags), col 100 = 1.0 (bias slot,
    // written once), rest zero pad. K = 4 tiles of 32.
    // A-waves (0-3): all 16 MFMAs (4 tiles x 4 gates) + cell update + h write.
    // B-waves (4-7): x loads/cvt -> 3 small LDS stores (1 step ahead) + output duty.
    __shared__ __align__(16) _Float16 Bop[2][NB * HPAD2];
    __shared__ __align__(16) float partb[2][16][20];   // [buf][seq][16 partials]

    const int tid  = threadIdx.x;
    const int w8   = tid >> 6;            // physical wave 0..7
    const int w    = w8 & 3;              // unit-slice 0..3
    const bool isA = w8 < 4;
    const int lane = tid & 63;
    const int g    = lane >> 4;           // k-group / D-row-group
    const int m    = lane & 15;           // seq (B col / D col)
    const int n0   = blockIdx.x * NB;
    const int u0   = 16 * w + 4 * g;      // first of 4 units an A-lane updates
    const int sigb = 32 * (w >> 1) + 8 * g + 4 * (w & 1);  // = phi(u0), 8B-aligned

    // ---- A-waves: all W fragments (4 gates x 4 K-tiles) ----
    f16x8 AW[4][4];
    f32x4 wdv = {0.f, 0.f, 0.f, 0.f};
    if (isA) {
        const float* Wc = W + 16 * w + m;     // tile e -> gate-col 64e + 16w + m
#pragma unroll
        for (int e = 0; e < 4; e++) {
#pragma unroll
            for (int c = 0; c < 2; c++) {     // h tiles: k 0..63 -> W row 40+k
                F8 hi;
#pragma unroll
                for (int i = 0; i < 8; i++) {
                    int k = 32 * c + 16 * (i >> 2) + 4 * g + (i & 3);
                    hi.e[i] = (_Float16)Wc[(40 + k) * 256 + 64 * e];
                }
                AW[e][c] = hi.v;
            }
            F8 xo, xA;
            float bv = b[64 * e + 16 * w + m] + (e == 2 ? 1.0f : 0.0f);
#pragma unroll
            for (int i = 0; i < 8; i++) {
                int kk = 16 * (i >> 2) + 4 * g + (i & 3);              // 0..31
                xo.e[i] = (_Float16)Wc[kk * 256 + 64 * e];             // obs dims
                xA.e[i] = (kk < ACTD) ? (_Float16)Wc[(OBS + kk) * 256 + 64 * e]
                        : (kk == 16)  ? (_Float16)bv                   // bias slot
                                      : (_Float16)0.0f;
            }
            AW[e][2] = xo.v;
            AW[e][3] = xA.v;
        }
        wdv = *(const f32x4*)&Wdec[u0];
    }
    const float bd = bdec_p[0];

    for (int i = tid; i < 2 * NB * HPAD2; i += 512)
        (&Bop[0][0])[i] = (_Float16)0.0f;
    __syncthreads();
    if (tid < 32)                          // bias B-val 1.0 at col 100, both buffers
        Bop[tid >> 4][(tid & 15) * HPAD2 + 100] = (_Float16)1.0f;

    // ---- B-wave x pipeline ----
    const float* pO = obss    + ((size_t)(n0 + m) * T_STEPS) * OBS  + 4 * g;
    const float* pA = actions + ((size_t)(n0 + m) * T_STEPS) * ACTD + 4 * g;
    f32x4 xo0 = {0,0,0,0}, xo1 = {0,0,0,0}, xa = {0,0,0,0};
    auto loadx = [&]() {
        xo0 = *(const f32x4*)pO;
        xo1 = *(const f32x4*)(pO + 16);
        pO += OBS;
        if (g < 2) { xa = *(const f32x4*)pA; pA += ACTD; }
    };
    f16x8 bxo;
    f16x4 uaq;
    auto cvtx = [&]() {
        F8 uo;
        uo.h2[0] = pkrtz(xo0[0], xo0[1]);
        uo.h2[1] = pkrtz(xo0[2], xo0[3]);
        uo.h2[2] = pkrtz(xo1[0], xo1[1]);
        uo.h2[3] = pkrtz(xo1[2], xo1[3]);
        F4 ua_;
        ua_.h2[0] = pkrtz(xa[0], xa[1]);
        ua_.h2[1] = pkrtz(xa[2], xa[3]);
        bxo = uo.v;
        uaq = ua_.v;
    };
    auto stagex = [&](int buf) {           // pi-permuted: frags land verbatim
        _Float16* xp = &Bop[buf][m * HPAD2 + 64];
        *(f16x8*)(xp + 8 * g) = bxo;                   // obs dims -> cols 64+8g..+7
        if (g < 2) *(f16x4*)(xp + 32 + 8 * g) = uaq;   // act dims -> cols 96+8g..+3
    };

    if (!isA) {
        loadx();          // x_0
        cvtx();
        stagex(0);        // x_0 into buffer 0
        loadx();          // x_1 (cvt'd + staged at t=0)
    }
    f32x4 cr = {0.f, 0.f, 0.f, 0.f};      // A: c' state (negated-c recurrence)
    float* pOut = out + (size_t)((w + 3) & 3) * NSEQ + n0 + lane;

    __syncthreads();
    if (isA) __builtin_amdgcn_s_setprio(1);

#pragma unroll 2
    for (int t = 0; t < T_STEPS; ++t) {
        const int cb  = t & 1;
        const int nb2 = cb ^ 1;
        // LDS-only barrier: B's global x loads may span it
        asm volatile("s_waitcnt lgkmcnt(0)\n\ts_barrier" ::: "memory");

        if (isA) {
            // one fragment set, shared by all 4 gate tiles
            const _Float16* bp = &Bop[cb][m * HPAD2];
            f16x8 f0 = *(const f16x8*)(bp + 8 * g);           // h k 0..31
            f16x8 f1 = *(const f16x8*)(bp + 32 + 8 * g);      // h k 32..63
            f16x8 f2 = *(const f16x8*)(bp + 64 + 8 * g);      // x obs
            f16x8 f3 = *(const f16x8*)(bp + 96 + 8 * g);      // x act + bias

            f32x4 acc[4];
#pragma unroll
            for (int e = 0; e < 4; e++) {
                const f32x4 z = {0.f, 0.f, 0.f, 0.f};
                f32x4 aA = __builtin_amdgcn_mfma_f32_16x16x32_f16(AW[e][2], f2, z, 0, 0, 0);
                f32x4 aB = __builtin_amdgcn_mfma_f32_16x16x32_f16(AW[e][3], f3, z, 0, 0, 0);
                aA = __builtin_amdgcn_mfma_f32_16x16x32_f16(AW[e][0], f0, aA, 0, 0, 0);
                aB = __builtin_amdgcn_mfma_f32_16x16x32_f16(AW[e][1], f1, aB, 0, 0, 0);
                acc[e] = aA + aB;
            }

            // cell update, fused single-rcp c (preserves R16's c' = -c recurrence)
            float h4[4];
#pragma unroll
            for (int r = 0; r < 4; r++) {
                float ef = __builtin_amdgcn_exp2f(acc[2][r] * -LOG2E);
                float ei = __builtin_amdgcn_exp2f(acc[0][r] * -LOG2E);
                float ej = __builtin_amdgcn_exp2f(acc[1][r] * (-2.0f * LOG2E));
                float Fv = 1.0f + ef, Av = 1.0f + ei, Bv = 1.0f + ej;
                float AB = Av * Bv;
                float num = fmaf(cr[r], AB, Fv * (Bv - 2.0f));
                float c = num * __builtin_amdgcn_rcpf(Fv * AB);
                cr[r] = c;
                float ec = __builtin_amdgcn_exp2f(c * (-2.0f * LOG2E));
                float eo = __builtin_amdgcn_exp2f(acc[3][r] * -LOG2E);
                float Dv = 1.0f + ec, Ev = 1.0f + eo;
                h4[r] = (Dv - 2.0f) * __builtin_amdgcn_rcpf(Dv * Ev);
            }
            // pack and write h as one b64 (phi layout)
            F4 hi_;
            hi_.h2[0] = pkrtz(h4[0], h4[1]);
            hi_.h2[1] = pkrtz(h4[2], h4[3]);
            *(f16x4*)(&Bop[nb2][m * HPAD2 + sigb]) = hi_.v;

            // decode partial: per-lane 4-FMA, direct LDS slot
            float p = h4[0] * wdv[0];
            p = fmaf(h4[1], wdv[1], p);
            p = fmaf(h4[2], wdv[2], p);
            p = fmaf(h4[3], wdv[3], p);
            partb[cb][m][4 * w + g] = p;
        } else {
            // producer: convert + stage x_{t+1}; issue x_{t+2} loads
            if (t + 1 < T_STEPS) {
                cvtx();
                stagex(nb2);
            }
            if (t + 2 < T_STEPS) loadx();

            // output duty (rotates): reduce prev step's 16 partials, store row t-1
            if (t > 0 && w == (t & 3) && lane < 16) {
                const float* pp = &partb[nb2][lane][0];
                f32x4 q0 = *(const f32x4*)pp;
                f32x4 q1 = *(const f32x4*)(pp + 4);
                f32x4 q2 = *(const f32x4*)(pp + 8);
                f32x4 q3 = *(const f32x4*)(pp + 12);
                f32x4 s4 = (q0 + q1) + (q2 + q3);
                *pOut = s4[0] + s4[1] + s4[2] + s4[3] + bd;
                pOut += 4 * NSEQ;
            }
        }
    }
    if (isA) __builtin_amdgcn_s_setprio(0);

    // final row (t = T_STEPS-1 partials live in partb[1]); B-wave 0 serves it
    __syncthreads();
    if (!isA && w == 0 && lane < 16) {
        const float* pp = &partb[1][lane][0];
        f32x4 q0 = *(const f32x4*)pp;
        f32x4 q1 = *(const f32x4*)(pp + 4);
        f32x4 q2 = *(const f32x4*)(pp + 8);
        f32x4 q3 = *(const f32x4*)(pp + 12);
        f32x4 s4 = (q0 + q1) + (q2 + q3);
        *pOut = s4[0] + s4[1] + s4[2] + s4[3] + bd;
    }
}

extern "C" void kernel_launch(void* const* d_in, const int* in_sizes, int n_in,
                              void* d_out, int out_size, void* d_ws, size_t ws_size,
                              hipStream_t stream) {
    (void)in_sizes; (void)n_in; (void)d_ws; (void)ws_size; (void)out_size;
    const float* obss    = (const float*)d_in[0];
    const float* actions = (const float*)d_in[1];
    const float* W       = (const float*)d_in[2];
    const float* b       = (const float*)d_in[3];
    const float* Wdec    = (const float*)d_in[4];
    const float* bdec    = (const float*)d_in[5];
    float* out = (float*)d_out;
    lstm_fused<<<dim3(NSEQ / NB), dim3(512), 0, stream>>>(obss, actions, W, b, Wdec, bdec, out);
}